// Round 5
// baseline (442.920 us; speedup 1.0000x reference)
//
#include <hip/hip_runtime.h>
#include <math.h>

#define NNODES 50000
#define NEDGES 800000
#define NTOT   850000   // edges + self-loops
#define NHEAD  8
#define HDIM   32
#define HHD    256      // NHEAD*HDIM
#define NCLS   40
#define NEG_SLOPE 0.2f

typedef _Float16 half4 __attribute__((ext_vector_type(4)));
typedef _Float16 half8 __attribute__((ext_vector_type(8)));
typedef short bf16x8 __attribute__((ext_vector_type(8)));
typedef float f32x16 __attribute__((ext_vector_type(16)));
typedef unsigned short u16;

__device__ __forceinline__ u16 f2bf(float x) {
    union { float f; unsigned u; } c; c.f = x;
    return (u16)(c.u >> 16);
}
__device__ __forceinline__ float bf2f(u16 h) {
    union { unsigned u; float f; } c; c.u = ((unsigned)h) << 16;
    return c.f;
}

// ---------------- CSR build ----------------

__global__ void k_init_counts(int* __restrict__ counts) {
    int i = blockIdx.x * 256 + threadIdx.x;
    if (i < NNODES) counts[i] = 1;   // self-loop
}

__global__ void k_count(const int* __restrict__ ei, int* __restrict__ counts) {
    int i = blockIdx.x * 256 + threadIdx.x;
    if (i < NEDGES) atomicAdd(&counts[ei[NEDGES + i]], 1);  // dst row
}

__global__ __launch_bounds__(256) void k_scan1(const int* __restrict__ counts,
                                               int* __restrict__ partial,
                                               int* __restrict__ bsums) {
    __shared__ int lds[256];
    int t = threadIdx.x;
    int i = blockIdx.x * 256 + t;
    int v = (i < NNODES) ? counts[i] : 0;
    lds[t] = v;
    __syncthreads();
    for (int off = 1; off < 256; off <<= 1) {
        int add = (t >= off) ? lds[t - off] : 0;
        __syncthreads();
        lds[t] += add;
        __syncthreads();
    }
    if (i < NNODES) partial[i] = lds[t] - v;   // exclusive within block
    if (t == 255) bsums[blockIdx.x] = lds[255];
}

__global__ __launch_bounds__(256) void k_scan2(const int* __restrict__ bsums,
                                               int* __restrict__ boff, int nb) {
    __shared__ int lds[256];
    int t = threadIdx.x;
    int v = (t < nb) ? bsums[t] : 0;
    lds[t] = v;
    __syncthreads();
    for (int off = 1; off < 256; off <<= 1) {
        int add = (t >= off) ? lds[t - off] : 0;
        __syncthreads();
        lds[t] += add;
        __syncthreads();
    }
    if (t < nb) boff[t] = lds[t] - v;
}

__global__ void k_scan3(int* __restrict__ row_ptr, const int* __restrict__ boff,
                        int* __restrict__ cursor) {
    int i = blockIdx.x * 256 + threadIdx.x;
    if (i < NNODES) {
        int r = row_ptr[i] + boff[blockIdx.x];
        row_ptr[i] = r;
        cursor[i] = r;
    }
    if (i == 0) row_ptr[NNODES] = NTOT;
}

__global__ void k_scatter(const int* __restrict__ ei, int* __restrict__ cursor,
                          int* __restrict__ esrc) {
    int i = blockIdx.x * 256 + threadIdx.x;
    if (i < NEDGES) {
        int s = ei[i];
        int d = ei[NEDGES + i];
        int pos = atomicAdd(&cursor[d], 1);
        esrc[pos] = s;
    }
}

__global__ void k_scatter_loops(int* __restrict__ cursor, int* __restrict__ esrc) {
    int i = blockIdx.x * 256 + threadIdx.x;
    if (i < NNODES) {
        int pos = atomicAdd(&cursor[i], 1);
        esrc[pos] = i;
    }
}

// ---------------- weight prep: transpose + bf16 hi/lo split ----------------
__global__ void k_prep_w(const float* __restrict__ W, u16* __restrict__ Bt_hi,
                         u16* __restrict__ Bt_lo, int K, int Nc, int Npad) {
    int idx = blockIdx.x * 256 + threadIdx.x;   // n*K + k
    if (idx >= Npad * K) return;
    int n = idx / K, k = idx - n * K;
    float w = (n < Nc) ? W[(size_t)k * Nc + n] : 0.f;
    u16 h = f2bf(w);
    float lo = w - bf2f(h);
    Bt_hi[idx] = h;
    Bt_lo[idx] = f2bf(lo);
}

// ---------------- MFMA split-bf16 GEMM ----------------
#define TBM 128
#define TBN 128
#define TBK 32
#define APAD 40

__global__ __launch_bounds__(256) void k_mfma_gemm(
    const float* __restrict__ A,
    const u16* __restrict__ Bt_hi,
    const u16* __restrict__ Bt_lo,
    const float* __restrict__ bias,
    _Float16* __restrict__ Ch,
    float* __restrict__ Cf,
    int M, int K, int NcReal, int ldc)
{
    __shared__ u16 Ahi[TBM][APAD];
    __shared__ u16 Alo[TBM][APAD];
    int t = threadIdx.x;
    int lane = t & 63;
    int wid = t >> 6;
    int wr = wid >> 1, wc = wid & 1;            // 2x2 wave grid
    int rowBase = blockIdx.y * TBM;
    int colBase = blockIdx.x * TBN;

    int arow = t >> 1;
    int akoff = (t & 1) * 16;
    bool arow_ok = (rowBase + arow) < M;
    const float* aptr = A + (size_t)(rowBase + arow) * K + akoff;

    f32x16 acc[2][2];
    #pragma unroll
    for (int i = 0; i < 2; ++i)
        #pragma unroll
        for (int j = 0; j < 2; ++j)
            #pragma unroll
            for (int r = 0; r < 16; ++r) acc[i][j][r] = 0.f;

    float4 areg[4];
    #pragma unroll
    for (int i = 0; i < 4; ++i)
        areg[i] = arow_ok ? *reinterpret_cast<const float4*>(aptr + i * 4)
                          : float4{0.f, 0.f, 0.f, 0.f};

    for (int k0 = 0; k0 < K; k0 += TBK) {
        #pragma unroll
        for (int i = 0; i < 4; ++i) {
            float vv[4] = {areg[i].x, areg[i].y, areg[i].z, areg[i].w};
            u16 h[4], l[4];
            #pragma unroll
            for (int c = 0; c < 4; ++c) {
                h[c] = f2bf(vv[c]);
                l[c] = f2bf(vv[c] - bf2f(h[c]));
            }
            *reinterpret_cast<uint2*>(&Ahi[arow][akoff + i * 4]) =
                uint2{(unsigned)h[0] | ((unsigned)h[1] << 16),
                      (unsigned)h[2] | ((unsigned)h[3] << 16)};
            *reinterpret_cast<uint2*>(&Alo[arow][akoff + i * 4]) =
                uint2{(unsigned)l[0] | ((unsigned)l[1] << 16),
                      (unsigned)l[2] | ((unsigned)l[3] << 16)};
        }
        __syncthreads();
        if (k0 + TBK < K) {
            const float* ap = aptr + k0 + TBK;
            #pragma unroll
            for (int i = 0; i < 4; ++i)
                areg[i] = arow_ok ? *reinterpret_cast<const float4*>(ap + i * 4)
                                  : float4{0.f, 0.f, 0.f, 0.f};
        }
        #pragma unroll
        for (int sub = 0; sub < 2; ++sub) {
            int kfo = sub * 16 + (lane >> 5) * 8;
            bf16x8 ah[2], al[2];
            #pragma unroll
            for (int rt = 0; rt < 2; ++rt) {
                int r = wr * 64 + rt * 32 + (lane & 31);
                ah[rt] = *reinterpret_cast<const bf16x8*>(&Ahi[r][kfo]);
                al[rt] = *reinterpret_cast<const bf16x8*>(&Alo[r][kfo]);
            }
            bf16x8 bh[2], bl[2];
            #pragma unroll
            for (int ct = 0; ct < 2; ++ct) {
                int n = colBase + wc * 64 + ct * 32 + (lane & 31);
                size_t boff = (size_t)n * K + k0 + kfo;
                bh[ct] = *reinterpret_cast<const bf16x8*>(Bt_hi + boff);
                bl[ct] = *reinterpret_cast<const bf16x8*>(Bt_lo + boff);
            }
            #pragma unroll
            for (int rt = 0; rt < 2; ++rt)
                #pragma unroll
                for (int ct = 0; ct < 2; ++ct) {
                    acc[rt][ct] = __builtin_amdgcn_mfma_f32_32x32x16_bf16(
                        ah[rt], bh[ct], acc[rt][ct], 0, 0, 0);
                    acc[rt][ct] = __builtin_amdgcn_mfma_f32_32x32x16_bf16(
                        ah[rt], bl[ct], acc[rt][ct], 0, 0, 0);
                    acc[rt][ct] = __builtin_amdgcn_mfma_f32_32x32x16_bf16(
                        al[rt], bh[ct], acc[rt][ct], 0, 0, 0);
                }
        }
        __syncthreads();
    }

    #pragma unroll
    for (int rt = 0; rt < 2; ++rt)
        #pragma unroll
        for (int ct = 0; ct < 2; ++ct) {
            int col = colBase + wc * 64 + ct * 32 + (lane & 31);
            #pragma unroll
            for (int r = 0; r < 16; ++r) {
                int row = rowBase + wr * 64 + rt * 32 +
                          (r & 3) + 8 * (r >> 2) + 4 * (lane >> 5);
                if (row >= M) continue;
                float v = acc[rt][ct][r];
                if (Ch) {
                    Ch[(size_t)row * ldc + col] = (_Float16)v;
                } else if (col < NcReal) {
                    Cf[(size_t)row * ldc + col] = v + bias[col];
                }
            }
        }
}

// ---------------- per-node attention coefficients (fp16 features) ----------
__global__ void k_alpha(const _Float16* __restrict__ xh,
                        const float* __restrict__ a_src,
                        const float* __restrict__ a_dst,
                        float* __restrict__ alpha_s,
                        float* __restrict__ alpha_d) {
    int idx = blockIdx.x * 256 + threadIdx.x;   // n*8 + h
    if (idx >= NNODES * NHEAD) return;
    int node = idx >> 3, h = idx & 7;
    const half4* p  = reinterpret_cast<const half4*>(xh + (size_t)node * HHD + h * HDIM);
    const float4* ps = reinterpret_cast<const float4*>(a_src + h * HDIM);
    const float4* pd = reinterpret_cast<const float4*>(a_dst + h * HDIM);
    float ss = 0.f, sd = 0.f;
    #pragma unroll
    for (int q = 0; q < 8; ++q) {
        half4 hv = p[q];
        float4 s4 = ps[q], d4 = pd[q];
        float vx = (float)hv.x, vy = (float)hv.y, vz = (float)hv.z, vw = (float)hv.w;
        ss += vx * s4.x + vy * s4.y + vz * s4.z + vw * s4.w;
        sd += vx * d4.x + vy * d4.y + vz * d4.z + vw * d4.w;
    }
    alpha_s[idx] = ss;
    alpha_d[idx] = sd;
}

// ---------------- edge softmax: unnormalized p + inverse denom -------------
// wave per node: lane = i_off*8 + h; iterates 8 edges x 8 heads per step.
// No max-subtraction: e is a small-scale dot (|e| << 80), exp cannot overflow.
__global__ __launch_bounds__(256) void k_softmax(const float* __restrict__ alpha_s,
                                                 const float* __restrict__ alpha_d,
                                                 const int* __restrict__ row_ptr,
                                                 const int* __restrict__ esrc,
                                                 float* __restrict__ alpha_e,
                                                 float* __restrict__ inv_denom) {
    int node = blockIdx.x * 4 + (threadIdx.x >> 6);
    if (node >= NNODES) return;
    int lane = threadIdx.x & 63;
    int i_off = lane >> 3;
    int h = lane & 7;
    int beg = row_ptr[node], end = row_ptr[node + 1];
    float ad = alpha_d[node * NHEAD + h];
    float sum = 0.f;
    for (int i = beg + i_off; i < end; i += 8) {
        int src = esrc[i];
        float e = alpha_s[src * NHEAD + h] + ad;
        e = (e > 0.f) ? e : NEG_SLOPE * e;
        float p = __expf(e);
        alpha_e[(size_t)i * NHEAD + h] = p;
        sum += p;
    }
    sum += __shfl_xor(sum, 8, 64);
    sum += __shfl_xor(sum, 16, 64);
    sum += __shfl_xor(sum, 32, 64);
    if (lane < 8) inv_denom[node * NHEAD + h] = 1.f / sum;
}

// ---------------- GAT aggregation: pure gather+fma ----------------
// 2 nodes per wave; lane (l in [0,32)) covers dims [8l, 8l+8) via one half8.
__global__ __launch_bounds__(256) void k_agg(const _Float16* __restrict__ xh,
                                             const float* __restrict__ alpha_e,
                                             const float* __restrict__ inv_denom,
                                             const int* __restrict__ row_ptr,
                                             const int* __restrict__ esrc,
                                             const float* __restrict__ bias,
                                             float* __restrict__ out) {
    int wave = blockIdx.x * 4 + (threadIdx.x >> 6);
    int node = wave * 2 + ((threadIdx.x & 63) >> 5);
    if (node >= NNODES) return;
    int l = threadIdx.x & 31;        // dim chunk [8l, 8l+8)
    int h = l >> 2;                  // head of this chunk
    int beg = row_ptr[node], end = row_ptr[node + 1];
    float acc[8] = {};
    for (int i = beg; i < end; ++i) {
        int src = esrc[i];
        float p = alpha_e[(size_t)i * NHEAD + h];
        half8 hv = *reinterpret_cast<const half8*>(xh + (size_t)src * HHD + l * 8);
        #pragma unroll
        for (int d = 0; d < 8; ++d)
            acc[d] += p * (float)hv[d];
    }
    float inv = inv_denom[node * NHEAD + h];
    float4 b0 = *reinterpret_cast<const float4*>(bias + l * 8);
    float4 b1 = *reinterpret_cast<const float4*>(bias + l * 8 + 4);
    float4 r0, r1;
    r0.x = fmaxf(acc[0] * inv + b0.x, 0.f);
    r0.y = fmaxf(acc[1] * inv + b0.y, 0.f);
    r0.z = fmaxf(acc[2] * inv + b0.z, 0.f);
    r0.w = fmaxf(acc[3] * inv + b0.w, 0.f);
    r1.x = fmaxf(acc[4] * inv + b1.x, 0.f);
    r1.y = fmaxf(acc[5] * inv + b1.y, 0.f);
    r1.z = fmaxf(acc[6] * inv + b1.z, 0.f);
    r1.w = fmaxf(acc[7] * inv + b1.w, 0.f);
    float* op = out + (size_t)node * HHD + l * 8;
    *reinterpret_cast<float4*>(op)     = r0;
    *reinterpret_cast<float4*>(op + 4) = r1;
}

// ---------------- launch ----------------

extern "C" void kernel_launch(void* const* d_in, const int* in_sizes, int n_in,
                              void* d_out, int out_size, void* d_ws, size_t ws_size,
                              hipStream_t stream) {
    const float* x   = (const float*)d_in[0];
    const int*   ei  = (const int*)  d_in[1];
    const float* W1  = (const float*)d_in[2];
    const float* a1s = (const float*)d_in[3];
    const float* a1d = (const float*)d_in[4];
    const float* b1  = (const float*)d_in[5];
    const float* W2  = (const float*)d_in[6];
    const float* a2s = (const float*)d_in[7];
    const float* a2d = (const float*)d_in[8];
    const float* b2  = (const float*)d_in[9];
    const float* Wc  = (const float*)d_in[10];
    const float* bc  = (const float*)d_in[11];
    float* out = (float*)d_out;

    char* ws = (char*)d_ws;
    size_t off = 0;
    auto alloc = [&](size_t bytes) -> void* {
        void* p = ws + off;
        off += (bytes + 255) & ~(size_t)255;
        return p;
    };
    _Float16* xh_h = (_Float16*)alloc((size_t)NNODES * HHD * 2);
    float* hbuf  = (float*)alloc((size_t)NNODES * HHD * 4);
    float* as_   = (float*)alloc((size_t)NNODES * NHEAD * 4);
    float* ad_   = (float*)alloc((size_t)NNODES * NHEAD * 4);
    float* alpha_e = (float*)alloc((size_t)NTOT * NHEAD * 4);
    float* invd  = (float*)alloc((size_t)NNODES * NHEAD * 4);
    int* counts  = (int*)alloc((size_t)NNODES * 4);
    int* row_ptr = (int*)alloc((size_t)(NNODES + 1) * 4);
    int* cursor  = (int*)alloc((size_t)NNODES * 4);
    int* esrc    = (int*)alloc((size_t)NTOT * 4);
    int* bsums   = (int*)alloc(256 * 4);
    int* boff    = (int*)alloc(256 * 4);
    u16* w1t_hi  = (u16*)alloc((size_t)HHD * 128 * 2);
    u16* w1t_lo  = (u16*)alloc((size_t)HHD * 128 * 2);
    u16* w2t_hi  = (u16*)alloc((size_t)HHD * HHD * 2);
    u16* w2t_lo  = (u16*)alloc((size_t)HHD * HHD * 2);
    u16* wct_hi  = (u16*)alloc((size_t)TBN * HHD * 2);
    u16* wct_lo  = (u16*)alloc((size_t)TBN * HHD * 2);
    (void)ws_size; (void)in_sizes; (void)n_in; (void)out_size;

    int gn = (NNODES + 255) / 256;
    int ge = (NEDGES + 255) / 256;

    // CSR build (same graph for both layers)
    k_init_counts<<<gn, 256, 0, stream>>>(counts);
    k_count<<<ge, 256, 0, stream>>>(ei, counts);
    k_scan1<<<gn, 256, 0, stream>>>(counts, row_ptr, bsums);
    k_scan2<<<1, 256, 0, stream>>>(bsums, boff, gn);
    k_scan3<<<gn, 256, 0, stream>>>(row_ptr, boff, cursor);
    k_scatter<<<ge, 256, 0, stream>>>(ei, cursor, esrc);
    k_scatter_loops<<<gn, 256, 0, stream>>>(cursor, esrc);

    // weight prep
    k_prep_w<<<(HHD * 128 + 255) / 256, 256, 0, stream>>>(W1, w1t_hi, w1t_lo, 128, HHD, HHD);
    k_prep_w<<<(HHD * HHD + 255) / 256, 256, 0, stream>>>(W2, w2t_hi, w2t_lo, HHD, HHD, HHD);
    k_prep_w<<<(TBN * HHD + 255) / 256, 256, 0, stream>>>(Wc, wct_hi, wct_lo, HHD, NCLS, TBN);

    dim3 gHid(HHD / TBN, (NNODES + TBM - 1) / TBM);   // (2, 391)
    dim3 gCls(1, (NNODES + TBM - 1) / TBM);           // (1, 391)
    int ga = (NNODES * NHEAD + 255) / 256;
    int gsm = (NNODES + 3) / 4;       // 4 nodes/block (wave per node)
    int gagg = NNODES / 8;            // 8 nodes/block (2 per wave)

    // layer 1
    k_mfma_gemm<<<gHid, 256, 0, stream>>>(x, w1t_hi, w1t_lo, nullptr, xh_h, nullptr,
                                          NNODES, 128, HHD, HHD);
    k_alpha<<<ga, 256, 0, stream>>>(xh_h, a1s, a1d, as_, ad_);
    k_softmax<<<gsm, 256, 0, stream>>>(as_, ad_, row_ptr, esrc, alpha_e, invd);
    k_agg<<<gagg, 256, 0, stream>>>(xh_h, alpha_e, invd, row_ptr, esrc, b1, hbuf);

    // layer 2
    k_mfma_gemm<<<gHid, 256, 0, stream>>>(hbuf, w2t_hi, w2t_lo, nullptr, xh_h, nullptr,
                                          NNODES, HHD, HHD, HHD);
    k_alpha<<<ga, 256, 0, stream>>>(xh_h, a2s, a2d, as_, ad_);
    k_softmax<<<gsm, 256, 0, stream>>>(as_, ad_, row_ptr, esrc, alpha_e, invd);
    k_agg<<<gagg, 256, 0, stream>>>(xh_h, alpha_e, invd, row_ptr, esrc, b2, hbuf);

    // classifier
    k_mfma_gemm<<<gCls, 256, 0, stream>>>(hbuf, wct_hi, wct_lo, bc, nullptr, out,
                                          NNODES, HHD, NCLS, NCLS);
}

// Round 6
// 385.172 us; speedup vs baseline: 1.1499x; 1.1499x over previous
//
#include <hip/hip_runtime.h>
#include <math.h>

#define NNODES 50000
#define NEDGES 800000
#define NTOT   850000   // edges + self-loops
#define NHEAD  8
#define HDIM   32
#define HHD    256      // NHEAD*HDIM
#define NCLS   40
#define NEG_SLOPE 0.2f

typedef _Float16 half4 __attribute__((ext_vector_type(4)));
typedef _Float16 half8 __attribute__((ext_vector_type(8)));
typedef short bf16x8 __attribute__((ext_vector_type(8)));
typedef float f32x16 __attribute__((ext_vector_type(16)));
typedef unsigned short u16;

__device__ __forceinline__ u16 f2bf(float x) {
    union { float f; unsigned u; } c; c.f = x;
    return (u16)(c.u >> 16);
}
__device__ __forceinline__ float bf2f(u16 h) {
    union { unsigned u; float f; } c; c.u = ((unsigned)h) << 16;
    return c.f;
}

// ---------------- CSR build ----------------

__global__ void k_init_counts(int* __restrict__ counts) {
    int i = blockIdx.x * 256 + threadIdx.x;
    if (i < NNODES) counts[i] = 1;   // self-loop
}

__global__ void k_count(const int* __restrict__ ei, int* __restrict__ counts) {
    int i = blockIdx.x * 256 + threadIdx.x;
    if (i < NEDGES) atomicAdd(&counts[ei[NEDGES + i]], 1);  // dst row
}

__global__ __launch_bounds__(256) void k_scan1(const int* __restrict__ counts,
                                               int* __restrict__ partial,
                                               int* __restrict__ bsums) {
    __shared__ int lds[256];
    int t = threadIdx.x;
    int i = blockIdx.x * 256 + t;
    int v = (i < NNODES) ? counts[i] : 0;
    lds[t] = v;
    __syncthreads();
    for (int off = 1; off < 256; off <<= 1) {
        int add = (t >= off) ? lds[t - off] : 0;
        __syncthreads();
        lds[t] += add;
        __syncthreads();
    }
    if (i < NNODES) partial[i] = lds[t] - v;   // exclusive within block
    if (t == 255) bsums[blockIdx.x] = lds[255];
}

__global__ __launch_bounds__(256) void k_scan2(const int* __restrict__ bsums,
                                               int* __restrict__ boff, int nb) {
    __shared__ int lds[256];
    int t = threadIdx.x;
    int v = (t < nb) ? bsums[t] : 0;
    lds[t] = v;
    __syncthreads();
    for (int off = 1; off < 256; off <<= 1) {
        int add = (t >= off) ? lds[t - off] : 0;
        __syncthreads();
        lds[t] += add;
        __syncthreads();
    }
    if (t < nb) boff[t] = lds[t] - v;
}

__global__ void k_scan3(int* __restrict__ row_ptr, const int* __restrict__ boff,
                        int* __restrict__ cursor) {
    int i = blockIdx.x * 256 + threadIdx.x;
    if (i < NNODES) {
        int r = row_ptr[i] + boff[blockIdx.x];
        row_ptr[i] = r;
        cursor[i] = r;
    }
    if (i == 0) row_ptr[NNODES] = NTOT;
}

__global__ void k_scatter(const int* __restrict__ ei, int* __restrict__ cursor,
                          int* __restrict__ esrc) {
    int i = blockIdx.x * 256 + threadIdx.x;
    if (i < NEDGES) {
        int s = ei[i];
        int d = ei[NEDGES + i];
        int pos = atomicAdd(&cursor[d], 1);
        esrc[pos] = s;
    }
}

__global__ void k_scatter_loops(int* __restrict__ cursor, int* __restrict__ esrc) {
    int i = blockIdx.x * 256 + threadIdx.x;
    if (i < NNODES) {
        int pos = atomicAdd(&cursor[i], 1);
        esrc[pos] = i;
    }
}

// ---------------- weight prep: transpose + bf16 hi/lo split ----------------
__global__ void k_prep_w(const float* __restrict__ W, u16* __restrict__ Bt_hi,
                         u16* __restrict__ Bt_lo, int K, int Nc, int Npad) {
    int idx = blockIdx.x * 256 + threadIdx.x;   // n*K + k
    if (idx >= Npad * K) return;
    int n = idx / K, k = idx - n * K;
    float w = (n < Nc) ? W[(size_t)k * Nc + n] : 0.f;
    u16 h = f2bf(w);
    float lo = w - bf2f(h);
    Bt_hi[idx] = h;
    Bt_lo[idx] = f2bf(lo);
}

// ---------------- MFMA split-bf16 GEMM (A: fp32 or fp16) ----------------
#define TBM 128
#define TBN 128
#define TBK 32
#define APAD 40

template <typename AT>
__global__ __launch_bounds__(256) void k_mfma_gemm(
    const AT* __restrict__ A,
    const u16* __restrict__ Bt_hi,
    const u16* __restrict__ Bt_lo,
    const float* __restrict__ bias,
    _Float16* __restrict__ Ch,
    float* __restrict__ Cf,
    int M, int K, int NcReal, int ldc)
{
    constexpr bool A_IS_F32 = sizeof(AT) == 4;
    __shared__ u16 Ahi[TBM][APAD];
    __shared__ u16 Alo[TBM][APAD];
    int t = threadIdx.x;
    int lane = t & 63;
    int wid = t >> 6;
    int wr = wid >> 1, wc = wid & 1;            // 2x2 wave grid
    int rowBase = blockIdx.y * TBM;
    int colBase = blockIdx.x * TBN;

    int arow = t >> 1;
    int akoff = (t & 1) * 16;
    bool arow_ok = (rowBase + arow) < M;
    const AT* aptr = A + (size_t)(rowBase + arow) * K + akoff;

    f32x16 acc[2][2];
    #pragma unroll
    for (int i = 0; i < 2; ++i)
        #pragma unroll
        for (int j = 0; j < 2; ++j)
            #pragma unroll
            for (int r = 0; r < 16; ++r) acc[i][j][r] = 0.f;

    float4 aregf[4];
    half8  aregh[2];
    auto load_a = [&](const AT* ap) {
        if constexpr (A_IS_F32) {
            #pragma unroll
            for (int i = 0; i < 4; ++i)
                aregf[i] = arow_ok ? *reinterpret_cast<const float4*>((const float*)ap + i * 4)
                                   : float4{0.f, 0.f, 0.f, 0.f};
        } else {
            #pragma unroll
            for (int i = 0; i < 2; ++i)
                aregh[i] = arow_ok ? *reinterpret_cast<const half8*>((const _Float16*)ap + i * 8)
                                   : half8{0, 0, 0, 0, 0, 0, 0, 0};
        }
    };
    load_a(aptr);

    for (int k0 = 0; k0 < K; k0 += TBK) {
        // ---- convert staged regs to hi/lo bf16 and write LDS ----
        float vv[16];
        if constexpr (A_IS_F32) {
            #pragma unroll
            for (int i = 0; i < 4; ++i) {
                vv[i * 4 + 0] = aregf[i].x; vv[i * 4 + 1] = aregf[i].y;
                vv[i * 4 + 2] = aregf[i].z; vv[i * 4 + 3] = aregf[i].w;
            }
        } else {
            #pragma unroll
            for (int i = 0; i < 2; ++i)
                #pragma unroll
                for (int c = 0; c < 8; ++c)
                    vv[i * 8 + c] = (float)aregh[i][c];
        }
        #pragma unroll
        for (int i = 0; i < 4; ++i) {
            u16 h[4], l[4];
            #pragma unroll
            for (int c = 0; c < 4; ++c) {
                float f = vv[i * 4 + c];
                h[c] = f2bf(f);
                l[c] = f2bf(f - bf2f(h[c]));
            }
            *reinterpret_cast<uint2*>(&Ahi[arow][akoff + i * 4]) =
                uint2{(unsigned)h[0] | ((unsigned)h[1] << 16),
                      (unsigned)h[2] | ((unsigned)h[3] << 16)};
            *reinterpret_cast<uint2*>(&Alo[arow][akoff + i * 4]) =
                uint2{(unsigned)l[0] | ((unsigned)l[1] << 16),
                      (unsigned)l[2] | ((unsigned)l[3] << 16)};
        }
        __syncthreads();
        if (k0 + TBK < K) load_a(aptr + k0 + TBK);
        #pragma unroll
        for (int sub = 0; sub < 2; ++sub) {
            int kfo = sub * 16 + (lane >> 5) * 8;
            bf16x8 ah[2], al[2];
            #pragma unroll
            for (int rt = 0; rt < 2; ++rt) {
                int r = wr * 64 + rt * 32 + (lane & 31);
                ah[rt] = *reinterpret_cast<const bf16x8*>(&Ahi[r][kfo]);
                al[rt] = *reinterpret_cast<const bf16x8*>(&Alo[r][kfo]);
            }
            bf16x8 bh[2], bl[2];
            #pragma unroll
            for (int ct = 0; ct < 2; ++ct) {
                int n = colBase + wc * 64 + ct * 32 + (lane & 31);
                size_t boff = (size_t)n * K + k0 + kfo;
                bh[ct] = *reinterpret_cast<const bf16x8*>(Bt_hi + boff);
                bl[ct] = *reinterpret_cast<const bf16x8*>(Bt_lo + boff);
            }
            #pragma unroll
            for (int rt = 0; rt < 2; ++rt)
                #pragma unroll
                for (int ct = 0; ct < 2; ++ct) {
                    acc[rt][ct] = __builtin_amdgcn_mfma_f32_32x32x16_bf16(
                        ah[rt], bh[ct], acc[rt][ct], 0, 0, 0);
                    acc[rt][ct] = __builtin_amdgcn_mfma_f32_32x32x16_bf16(
                        ah[rt], bl[ct], acc[rt][ct], 0, 0, 0);
                    acc[rt][ct] = __builtin_amdgcn_mfma_f32_32x32x16_bf16(
                        al[rt], bh[ct], acc[rt][ct], 0, 0, 0);
                }
        }
        __syncthreads();
    }

    #pragma unroll
    for (int rt = 0; rt < 2; ++rt)
        #pragma unroll
        for (int ct = 0; ct < 2; ++ct) {
            int col = colBase + wc * 64 + ct * 32 + (lane & 31);
            #pragma unroll
            for (int r = 0; r < 16; ++r) {
                int row = rowBase + wr * 64 + rt * 32 +
                          (r & 3) + 8 * (r >> 2) + 4 * (lane >> 5);
                if (row >= M) continue;
                float v = acc[rt][ct][r];
                if (Ch) {
                    Ch[(size_t)row * ldc + col] = (_Float16)v;
                } else if (col < NcReal) {
                    Cf[(size_t)row * ldc + col] = v + bias[col];
                }
            }
        }
}

// ---------------- per-node attention coefficients (fp16 features) ----------
__global__ void k_alpha(const _Float16* __restrict__ xh,
                        const float* __restrict__ a_src,
                        const float* __restrict__ a_dst,
                        float* __restrict__ alpha_s,
                        float* __restrict__ alpha_d) {
    int idx = blockIdx.x * 256 + threadIdx.x;   // n*8 + h
    if (idx >= NNODES * NHEAD) return;
    int node = idx >> 3, h = idx & 7;
    const half4* p  = reinterpret_cast<const half4*>(xh + (size_t)node * HHD + h * HDIM);
    const float4* ps = reinterpret_cast<const float4*>(a_src + h * HDIM);
    const float4* pd = reinterpret_cast<const float4*>(a_dst + h * HDIM);
    float ss = 0.f, sd = 0.f;
    #pragma unroll
    for (int q = 0; q < 8; ++q) {
        half4 hv = p[q];
        float4 s4 = ps[q], d4 = pd[q];
        float vx = (float)hv.x, vy = (float)hv.y, vz = (float)hv.z, vw = (float)hv.w;
        ss += vx * s4.x + vy * s4.y + vz * s4.z + vw * s4.w;
        sd += vx * d4.x + vy * d4.y + vz * d4.z + vw * d4.w;
    }
    alpha_s[idx] = ss;
    alpha_d[idx] = sd;
}

// ---------------- GAT aggregation: fused single-pass softmax + gather ------
// 2 nodes per wave; lane l in [0,32) covers dims [8l, 8l+8) via one half8.
// No max-subtraction: e is a small-scale dot (|e| << 80), exp cannot overflow.
// Manual 4-way unroll for memory-level parallelism (4 gathers in flight).
__global__ __launch_bounds__(256) void k_agg(const _Float16* __restrict__ xh,
                                             const float* __restrict__ alpha_s,
                                             const float* __restrict__ alpha_d,
                                             const int* __restrict__ row_ptr,
                                             const int* __restrict__ esrc,
                                             const float* __restrict__ bias,
                                             _Float16* __restrict__ out) {
    int wave = blockIdx.x * 4 + (threadIdx.x >> 6);
    int node = wave * 2 + ((threadIdx.x & 63) >> 5);
    if (node >= NNODES) return;
    int l = threadIdx.x & 31;        // dim chunk [8l, 8l+8)
    int h = l >> 2;                  // head of this chunk
    int beg = row_ptr[node], end = row_ptr[node + 1];
    float ad = alpha_d[node * NHEAD + h];
    float acc[8] = {};
    float ssum = 0.f;
    int i = beg;
    for (; i + 3 < end; i += 4) {
        int s0 = esrc[i], s1 = esrc[i + 1], s2 = esrc[i + 2], s3 = esrc[i + 3];
        float e0 = alpha_s[s0 * NHEAD + h] + ad;
        float e1 = alpha_s[s1 * NHEAD + h] + ad;
        float e2 = alpha_s[s2 * NHEAD + h] + ad;
        float e3 = alpha_s[s3 * NHEAD + h] + ad;
        half8 v0 = *reinterpret_cast<const half8*>(xh + (size_t)s0 * HHD + l * 8);
        half8 v1 = *reinterpret_cast<const half8*>(xh + (size_t)s1 * HHD + l * 8);
        half8 v2 = *reinterpret_cast<const half8*>(xh + (size_t)s2 * HHD + l * 8);
        half8 v3 = *reinterpret_cast<const half8*>(xh + (size_t)s3 * HHD + l * 8);
        e0 = (e0 > 0.f) ? e0 : NEG_SLOPE * e0;
        e1 = (e1 > 0.f) ? e1 : NEG_SLOPE * e1;
        e2 = (e2 > 0.f) ? e2 : NEG_SLOPE * e2;
        e3 = (e3 > 0.f) ? e3 : NEG_SLOPE * e3;
        float p0 = __expf(e0), p1 = __expf(e1), p2 = __expf(e2), p3 = __expf(e3);
        ssum += (p0 + p1) + (p2 + p3);
        #pragma unroll
        for (int d = 0; d < 8; ++d)
            acc[d] += p0 * (float)v0[d] + p1 * (float)v1[d] +
                      p2 * (float)v2[d] + p3 * (float)v3[d];
    }
    for (; i < end; ++i) {
        int s0 = esrc[i];
        float e0 = alpha_s[s0 * NHEAD + h] + ad;
        half8 v0 = *reinterpret_cast<const half8*>(xh + (size_t)s0 * HHD + l * 8);
        e0 = (e0 > 0.f) ? e0 : NEG_SLOPE * e0;
        float p0 = __expf(e0);
        ssum += p0;
        #pragma unroll
        for (int d = 0; d < 8; ++d)
            acc[d] += p0 * (float)v0[d];
    }
    float inv = 1.f / ssum;
    float4 b0 = *reinterpret_cast<const float4*>(bias + l * 8);
    float4 b1 = *reinterpret_cast<const float4*>(bias + l * 8 + 4);
    float bb[8] = {b0.x, b0.y, b0.z, b0.w, b1.x, b1.y, b1.z, b1.w};
    half8 r;
    #pragma unroll
    for (int d = 0; d < 8; ++d)
        r[d] = (_Float16)fmaxf(acc[d] * inv + bb[d], 0.f);
    *reinterpret_cast<half8*>(out + (size_t)node * HHD + l * 8) = r;
}

// ---------------- launch ----------------

extern "C" void kernel_launch(void* const* d_in, const int* in_sizes, int n_in,
                              void* d_out, int out_size, void* d_ws, size_t ws_size,
                              hipStream_t stream) {
    const float* x   = (const float*)d_in[0];
    const int*   ei  = (const int*)  d_in[1];
    const float* W1  = (const float*)d_in[2];
    const float* a1s = (const float*)d_in[3];
    const float* a1d = (const float*)d_in[4];
    const float* b1  = (const float*)d_in[5];
    const float* W2  = (const float*)d_in[6];
    const float* a2s = (const float*)d_in[7];
    const float* a2d = (const float*)d_in[8];
    const float* b2  = (const float*)d_in[9];
    const float* Wc  = (const float*)d_in[10];
    const float* bc  = (const float*)d_in[11];
    float* out = (float*)d_out;

    char* ws = (char*)d_ws;
    size_t off = 0;
    auto alloc = [&](size_t bytes) -> void* {
        void* p = ws + off;
        off += (bytes + 255) & ~(size_t)255;
        return p;
    };
    _Float16* xh_h  = (_Float16*)alloc((size_t)NNODES * HHD * 2);
    _Float16* hbuf_h = (_Float16*)alloc((size_t)NNODES * HHD * 2);
    float* as_   = (float*)alloc((size_t)NNODES * NHEAD * 4);
    float* ad_   = (float*)alloc((size_t)NNODES * NHEAD * 4);
    int* counts  = (int*)alloc((size_t)NNODES * 4);
    int* row_ptr = (int*)alloc((size_t)(NNODES + 1) * 4);
    int* cursor  = (int*)alloc((size_t)NNODES * 4);
    int* esrc    = (int*)alloc((size_t)NTOT * 4);
    int* bsums   = (int*)alloc(256 * 4);
    int* boff    = (int*)alloc(256 * 4);
    u16* w1t_hi  = (u16*)alloc((size_t)HHD * 128 * 2);
    u16* w1t_lo  = (u16*)alloc((size_t)HHD * 128 * 2);
    u16* w2t_hi  = (u16*)alloc((size_t)HHD * HHD * 2);
    u16* w2t_lo  = (u16*)alloc((size_t)HHD * HHD * 2);
    u16* wct_hi  = (u16*)alloc((size_t)TBN * HHD * 2);
    u16* wct_lo  = (u16*)alloc((size_t)TBN * HHD * 2);
    (void)ws_size; (void)in_sizes; (void)n_in; (void)out_size;

    int gn = (NNODES + 255) / 256;
    int ge = (NEDGES + 255) / 256;

    // CSR build (same graph for both layers)
    k_init_counts<<<gn, 256, 0, stream>>>(counts);
    k_count<<<ge, 256, 0, stream>>>(ei, counts);
    k_scan1<<<gn, 256, 0, stream>>>(counts, row_ptr, bsums);
    k_scan2<<<1, 256, 0, stream>>>(bsums, boff, gn);
    k_scan3<<<gn, 256, 0, stream>>>(row_ptr, boff, cursor);
    k_scatter<<<ge, 256, 0, stream>>>(ei, cursor, esrc);
    k_scatter_loops<<<gn, 256, 0, stream>>>(cursor, esrc);

    // weight prep
    k_prep_w<<<(HHD * 128 + 255) / 256, 256, 0, stream>>>(W1, w1t_hi, w1t_lo, 128, HHD, HHD);
    k_prep_w<<<(HHD * HHD + 255) / 256, 256, 0, stream>>>(W2, w2t_hi, w2t_lo, HHD, HHD, HHD);
    k_prep_w<<<(TBN * HHD + 255) / 256, 256, 0, stream>>>(Wc, wct_hi, wct_lo, HHD, NCLS, TBN);

    dim3 gHid(HHD / TBN, (NNODES + TBM - 1) / TBM);   // (2, 391)
    dim3 gCls(1, (NNODES + TBM - 1) / TBM);           // (1, 391)
    int ga = (NNODES * NHEAD + 255) / 256;
    int gagg = NNODES / 8;            // 8 nodes/block (2 per wave)

    // layer 1
    k_mfma_gemm<float><<<gHid, 256, 0, stream>>>(x, w1t_hi, w1t_lo, nullptr, xh_h, nullptr,
                                                 NNODES, 128, HHD, HHD);
    k_alpha<<<ga, 256, 0, stream>>>(xh_h, a1s, a1d, as_, ad_);
    k_agg<<<gagg, 256, 0, stream>>>(xh_h, as_, ad_, row_ptr, esrc, b1, hbuf_h);

    // layer 2
    k_mfma_gemm<_Float16><<<gHid, 256, 0, stream>>>(hbuf_h, w2t_hi, w2t_lo, nullptr, xh_h, nullptr,
                                                    NNODES, HHD, HHD, HHD);
    k_alpha<<<ga, 256, 0, stream>>>(xh_h, a2s, a2d, as_, ad_);
    k_agg<<<gagg, 256, 0, stream>>>(xh_h, as_, ad_, row_ptr, esrc, b2, hbuf_h);

    // classifier
    k_mfma_gemm<_Float16><<<gCls, 256, 0, stream>>>(hbuf_h, wct_hi, wct_lo, bc, nullptr, out,
                                                    NNODES, HHD, NCLS, NCLS);
}

// Round 7
// 351.224 us; speedup vs baseline: 1.2611x; 1.0967x over previous
//
#include <hip/hip_runtime.h>
#include <math.h>

#define NNODES 50000
#define NEDGES 800000
#define NTOT   850000   // edges + self-loops
#define NHEAD  8
#define HDIM   32
#define HHD    256      // NHEAD*HDIM
#define NCLS   40
#define NEG_SLOPE 0.2f

typedef _Float16 half4 __attribute__((ext_vector_type(4)));
typedef _Float16 half8 __attribute__((ext_vector_type(8)));
typedef float f32x16 __attribute__((ext_vector_type(16)));
typedef unsigned short u16;

// ---------------- CSR build ----------------

__global__ void k_init_counts(int* __restrict__ counts) {
    int i = blockIdx.x * 256 + threadIdx.x;
    if (i < NNODES) counts[i] = 1;   // self-loop
}

__global__ void k_count(const int* __restrict__ ei, int* __restrict__ counts) {
    int i = blockIdx.x * 256 + threadIdx.x;
    if (i < NEDGES) atomicAdd(&counts[ei[NEDGES + i]], 1);  // dst row
}

__global__ __launch_bounds__(256) void k_scan1(const int* __restrict__ counts,
                                               int* __restrict__ partial,
                                               int* __restrict__ bsums) {
    __shared__ int lds[256];
    int t = threadIdx.x;
    int i = blockIdx.x * 256 + t;
    int v = (i < NNODES) ? counts[i] : 0;
    lds[t] = v;
    __syncthreads();
    for (int off = 1; off < 256; off <<= 1) {
        int add = (t >= off) ? lds[t - off] : 0;
        __syncthreads();
        lds[t] += add;
        __syncthreads();
    }
    if (i < NNODES) partial[i] = lds[t] - v;   // exclusive within block
    if (t == 255) bsums[blockIdx.x] = lds[255];
}

__global__ __launch_bounds__(256) void k_scan2(const int* __restrict__ bsums,
                                               int* __restrict__ boff, int nb) {
    __shared__ int lds[256];
    int t = threadIdx.x;
    int v = (t < nb) ? bsums[t] : 0;
    lds[t] = v;
    __syncthreads();
    for (int off = 1; off < 256; off <<= 1) {
        int add = (t >= off) ? lds[t - off] : 0;
        __syncthreads();
        lds[t] += add;
        __syncthreads();
    }
    if (t < nb) boff[t] = lds[t] - v;
}

__global__ void k_scan3(int* __restrict__ row_ptr, const int* __restrict__ boff,
                        int* __restrict__ cursor) {
    int i = blockIdx.x * 256 + threadIdx.x;
    if (i < NNODES) {
        int r = row_ptr[i] + boff[blockIdx.x];
        row_ptr[i] = r;
        cursor[i] = r;
    }
    if (i == 0) row_ptr[NNODES] = NTOT;
}

// fused: regular edges + self-loops
__global__ void k_scatter(const int* __restrict__ ei, int* __restrict__ cursor,
                          int* __restrict__ esrc) {
    int i = blockIdx.x * 256 + threadIdx.x;
    if (i < NEDGES) {
        int s = ei[i];
        int d = ei[NEDGES + i];
        int pos = atomicAdd(&cursor[d], 1);
        esrc[pos] = s;
    } else if (i < NTOT) {
        int n = i - NEDGES;
        int pos = atomicAdd(&cursor[n], 1);
        esrc[pos] = n;
    }
}

// ---------------- weight prep: transpose + fp16 convert ----------------
// W[K,Nc] fp32 -> Wt [Npad][K] fp16 (k-contiguous rows)
__global__ void k_prep_w(const float* __restrict__ W, _Float16* __restrict__ Wt,
                         int K, int Nc, int Npad) {
    int idx = blockIdx.x * 256 + threadIdx.x;   // n*K + k
    if (idx >= Npad * K) return;
    int n = idx / K, k = idx - n * K;
    float w = (n < Nc) ? W[(size_t)k * Nc + n] : 0.f;
    Wt[idx] = (_Float16)w;
}

// ---------------- MFMA f16 GEMM (A: fp32 or fp16) ----------------
// C[M,*] = A[M,K] @ B[K,*];  B pre-transposed/fp16: Wt[n][k].
// mfma_f32_32x32x16_f16: fp16 inputs multiply exactly into fp32 acc.
#define TBM 128
#define TBN 128
#define TBK 32
#define APAD 34   // 68 B row stride = 17 banks (odd) -> conflict-free b128

template <typename AT>
__global__ __launch_bounds__(256) void k_mfma_gemm(
    const AT* __restrict__ A,
    const _Float16* __restrict__ Wt,
    const float* __restrict__ bias,
    _Float16* __restrict__ Ch,
    float* __restrict__ Cf,
    int M, int K, int NcReal, int ldc)
{
    constexpr bool A_IS_F32 = sizeof(AT) == 4;
    __shared__ _Float16 Ah[TBM][APAD];
    int t = threadIdx.x;
    int lane = t & 63;
    int wid = t >> 6;
    int wr = wid >> 1, wc = wid & 1;            // 2x2 wave grid
    int rowBase = blockIdx.y * TBM;
    int colBase = blockIdx.x * TBN;

    int arow = t >> 1;
    int akoff = (t & 1) * 16;
    bool arow_ok = (rowBase + arow) < M;
    const AT* aptr = A + (size_t)(rowBase + arow) * K + akoff;

    f32x16 acc[2][2];
    #pragma unroll
    for (int i = 0; i < 2; ++i)
        #pragma unroll
        for (int j = 0; j < 2; ++j)
            #pragma unroll
            for (int r = 0; r < 16; ++r) acc[i][j][r] = 0.f;

    float4 aregf[4];
    half8  aregh[2];
    auto load_a = [&](const AT* ap) {
        if constexpr (A_IS_F32) {
            #pragma unroll
            for (int i = 0; i < 4; ++i)
                aregf[i] = arow_ok ? *reinterpret_cast<const float4*>((const float*)ap + i * 4)
                                   : float4{0.f, 0.f, 0.f, 0.f};
        } else {
            #pragma unroll
            for (int i = 0; i < 2; ++i)
                aregh[i] = arow_ok ? *reinterpret_cast<const half8*>((const _Float16*)ap + i * 8)
                                   : half8{0, 0, 0, 0, 0, 0, 0, 0};
        }
    };
    load_a(aptr);

    for (int k0 = 0; k0 < K; k0 += TBK) {
        // ---- write staged regs to LDS as fp16 ----
        if constexpr (A_IS_F32) {
            half8 h0, h1;
            #pragma unroll
            for (int c = 0; c < 4; ++c) {
                float4 v = aregf[c];
                if (c < 2) {
                    h0[c * 4 + 0] = (_Float16)v.x; h0[c * 4 + 1] = (_Float16)v.y;
                    h0[c * 4 + 2] = (_Float16)v.z; h0[c * 4 + 3] = (_Float16)v.w;
                } else {
                    h1[(c - 2) * 4 + 0] = (_Float16)v.x; h1[(c - 2) * 4 + 1] = (_Float16)v.y;
                    h1[(c - 2) * 4 + 2] = (_Float16)v.z; h1[(c - 2) * 4 + 3] = (_Float16)v.w;
                }
            }
            *reinterpret_cast<half8*>(&Ah[arow][akoff])     = h0;
            *reinterpret_cast<half8*>(&Ah[arow][akoff + 8]) = h1;
        } else {
            *reinterpret_cast<half8*>(&Ah[arow][akoff])     = aregh[0];
            *reinterpret_cast<half8*>(&Ah[arow][akoff + 8]) = aregh[1];
        }
        __syncthreads();
        if (k0 + TBK < K) load_a(aptr + k0 + TBK);
        #pragma unroll
        for (int sub = 0; sub < 2; ++sub) {
            int kfo = sub * 16 + (lane >> 5) * 8;
            half8 ah[2];
            #pragma unroll
            for (int rt = 0; rt < 2; ++rt) {
                int r = wr * 64 + rt * 32 + (lane & 31);
                ah[rt] = *reinterpret_cast<const half8*>(&Ah[r][kfo]);
            }
            half8 bh[2];
            #pragma unroll
            for (int ct = 0; ct < 2; ++ct) {
                int n = colBase + wc * 64 + ct * 32 + (lane & 31);
                bh[ct] = *reinterpret_cast<const half8*>(Wt + (size_t)n * K + k0 + kfo);
            }
            #pragma unroll
            for (int rt = 0; rt < 2; ++rt)
                #pragma unroll
                for (int ct = 0; ct < 2; ++ct)
                    acc[rt][ct] = __builtin_amdgcn_mfma_f32_32x32x16_f16(
                        ah[rt], bh[ct], acc[rt][ct], 0, 0, 0);
        }
        __syncthreads();
    }

    // ---- epilogue: C/D layout col=lane&31, row=(r&3)+8*(r>>2)+4*(lane>>5) ----
    #pragma unroll
    for (int rt = 0; rt < 2; ++rt)
        #pragma unroll
        for (int ct = 0; ct < 2; ++ct) {
            int col = colBase + wc * 64 + ct * 32 + (lane & 31);
            #pragma unroll
            for (int r = 0; r < 16; ++r) {
                int row = rowBase + wr * 64 + rt * 32 +
                          (r & 3) + 8 * (r >> 2) + 4 * (lane >> 5);
                if (row >= M) continue;
                float v = acc[rt][ct][r];
                if (Ch) {
                    Ch[(size_t)row * ldc + col] = (_Float16)v;
                } else if (col < NcReal) {
                    Cf[(size_t)row * ldc + col] = v + bias[col];
                }
            }
        }
}

// ---------------- per-node attention coefficients (fp16 features) ----------
__global__ void k_alpha(const _Float16* __restrict__ xh,
                        const float* __restrict__ a_src,
                        const float* __restrict__ a_dst,
                        float* __restrict__ alpha_s,
                        float* __restrict__ alpha_d) {
    int idx = blockIdx.x * 256 + threadIdx.x;   // n*8 + h
    if (idx >= NNODES * NHEAD) return;
    int node = idx >> 3, h = idx & 7;
    const half4* p  = reinterpret_cast<const half4*>(xh + (size_t)node * HHD + h * HDIM);
    const float4* ps = reinterpret_cast<const float4*>(a_src + h * HDIM);
    const float4* pd = reinterpret_cast<const float4*>(a_dst + h * HDIM);
    float ss = 0.f, sd = 0.f;
    #pragma unroll
    for (int q = 0; q < 8; ++q) {
        half4 hv = p[q];
        float4 s4 = ps[q], d4 = pd[q];
        float vx = (float)hv.x, vy = (float)hv.y, vz = (float)hv.z, vw = (float)hv.w;
        ss += vx * s4.x + vy * s4.y + vz * s4.z + vw * s4.w;
        sd += vx * d4.x + vy * d4.y + vz * d4.z + vw * d4.w;
    }
    alpha_s[idx] = ss;
    alpha_d[idx] = sd;
}

// ---------------- GAT aggregation: fused single-pass softmax + gather ------
// 2 nodes per wave; lane l in [0,32) covers dims [8l, 8l+8) via one half8.
// No max-subtraction: e is a small-scale dot (|e| << 80), exp cannot overflow.
// Manual 4-way unroll for memory-level parallelism (4 gathers in flight).
__global__ __launch_bounds__(256) void k_agg(const _Float16* __restrict__ xh,
                                             const float* __restrict__ alpha_s,
                                             const float* __restrict__ alpha_d,
                                             const int* __restrict__ row_ptr,
                                             const int* __restrict__ esrc,
                                             const float* __restrict__ bias,
                                             _Float16* __restrict__ out) {
    int wave = blockIdx.x * 4 + (threadIdx.x >> 6);
    int node = wave * 2 + ((threadIdx.x & 63) >> 5);
    if (node >= NNODES) return;
    int l = threadIdx.x & 31;        // dim chunk [8l, 8l+8)
    int h = l >> 2;                  // head of this chunk
    int beg = row_ptr[node], end = row_ptr[node + 1];
    float ad = alpha_d[node * NHEAD + h];
    float acc[8] = {};
    float ssum = 0.f;
    int i = beg;
    for (; i + 3 < end; i += 4) {
        int s0 = esrc[i], s1 = esrc[i + 1], s2 = esrc[i + 2], s3 = esrc[i + 3];
        float e0 = alpha_s[s0 * NHEAD + h] + ad;
        float e1 = alpha_s[s1 * NHEAD + h] + ad;
        float e2 = alpha_s[s2 * NHEAD + h] + ad;
        float e3 = alpha_s[s3 * NHEAD + h] + ad;
        half8 v0 = *reinterpret_cast<const half8*>(xh + (size_t)s0 * HHD + l * 8);
        half8 v1 = *reinterpret_cast<const half8*>(xh + (size_t)s1 * HHD + l * 8);
        half8 v2 = *reinterpret_cast<const half8*>(xh + (size_t)s2 * HHD + l * 8);
        half8 v3 = *reinterpret_cast<const half8*>(xh + (size_t)s3 * HHD + l * 8);
        e0 = (e0 > 0.f) ? e0 : NEG_SLOPE * e0;
        e1 = (e1 > 0.f) ? e1 : NEG_SLOPE * e1;
        e2 = (e2 > 0.f) ? e2 : NEG_SLOPE * e2;
        e3 = (e3 > 0.f) ? e3 : NEG_SLOPE * e3;
        float p0 = __expf(e0), p1 = __expf(e1), p2 = __expf(e2), p3 = __expf(e3);
        ssum += (p0 + p1) + (p2 + p3);
        #pragma unroll
        for (int d = 0; d < 8; ++d)
            acc[d] += p0 * (float)v0[d] + p1 * (float)v1[d] +
                      p2 * (float)v2[d] + p3 * (float)v3[d];
    }
    for (; i < end; ++i) {
        int s0 = esrc[i];
        float e0 = alpha_s[s0 * NHEAD + h] + ad;
        half8 v0 = *reinterpret_cast<const half8*>(xh + (size_t)s0 * HHD + l * 8);
        e0 = (e0 > 0.f) ? e0 : NEG_SLOPE * e0;
        float p0 = __expf(e0);
        ssum += p0;
        #pragma unroll
        for (int d = 0; d < 8; ++d)
            acc[d] += p0 * (float)v0[d];
    }
    float inv = 1.f / ssum;
    float4 b0 = *reinterpret_cast<const float4*>(bias + l * 8);
    float4 b1 = *reinterpret_cast<const float4*>(bias + l * 8 + 4);
    float bb[8] = {b0.x, b0.y, b0.z, b0.w, b1.x, b1.y, b1.z, b1.w};
    half8 r;
    #pragma unroll
    for (int d = 0; d < 8; ++d)
        r[d] = (_Float16)fmaxf(acc[d] * inv + bb[d], 0.f);
    *reinterpret_cast<half8*>(out + (size_t)node * HHD + l * 8) = r;
}

// ---------------- launch ----------------

extern "C" void kernel_launch(void* const* d_in, const int* in_sizes, int n_in,
                              void* d_out, int out_size, void* d_ws, size_t ws_size,
                              hipStream_t stream) {
    const float* x   = (const float*)d_in[0];
    const int*   ei  = (const int*)  d_in[1];
    const float* W1  = (const float*)d_in[2];
    const float* a1s = (const float*)d_in[3];
    const float* a1d = (const float*)d_in[4];
    const float* b1  = (const float*)d_in[5];
    const float* W2  = (const float*)d_in[6];
    const float* a2s = (const float*)d_in[7];
    const float* a2d = (const float*)d_in[8];
    const float* b2  = (const float*)d_in[9];
    const float* Wc  = (const float*)d_in[10];
    const float* bc  = (const float*)d_in[11];
    float* out = (float*)d_out;

    char* ws = (char*)d_ws;
    size_t off = 0;
    auto alloc = [&](size_t bytes) -> void* {
        void* p = ws + off;
        off += (bytes + 255) & ~(size_t)255;
        return p;
    };
    _Float16* xh_h   = (_Float16*)alloc((size_t)NNODES * HHD * 2);
    _Float16* hbuf_h = (_Float16*)alloc((size_t)NNODES * HHD * 2);
    float* as_   = (float*)alloc((size_t)NNODES * NHEAD * 4);
    float* ad_   = (float*)alloc((size_t)NNODES * NHEAD * 4);
    int* counts  = (int*)alloc((size_t)NNODES * 4);
    int* row_ptr = (int*)alloc((size_t)(NNODES + 1) * 4);
    int* cursor  = (int*)alloc((size_t)NNODES * 4);
    int* esrc    = (int*)alloc((size_t)NTOT * 4);
    int* bsums   = (int*)alloc(256 * 4);
    int* boff    = (int*)alloc(256 * 4);
    _Float16* w1t = (_Float16*)alloc((size_t)HHD * 128 * 2);   // [256][128]
    _Float16* w2t = (_Float16*)alloc((size_t)HHD * HHD * 2);   // [256][256]
    _Float16* wct = (_Float16*)alloc((size_t)TBN * HHD * 2);   // [128][256] padded
    (void)ws_size; (void)in_sizes; (void)n_in; (void)out_size;

    int gn = (NNODES + 255) / 256;
    int ge = (NEDGES + 255) / 256;
    int gt = (NTOT + 255) / 256;

    // CSR build (same graph for both layers)
    k_init_counts<<<gn, 256, 0, stream>>>(counts);
    k_count<<<ge, 256, 0, stream>>>(ei, counts);
    k_scan1<<<gn, 256, 0, stream>>>(counts, row_ptr, bsums);
    k_scan2<<<1, 256, 0, stream>>>(bsums, boff, gn);
    k_scan3<<<gn, 256, 0, stream>>>(row_ptr, boff, cursor);
    k_scatter<<<gt, 256, 0, stream>>>(ei, cursor, esrc);

    // weight prep (transpose + fp16)
    k_prep_w<<<(HHD * 128 + 255) / 256, 256, 0, stream>>>(W1, w1t, 128, HHD, HHD);
    k_prep_w<<<(HHD * HHD + 255) / 256, 256, 0, stream>>>(W2, w2t, HHD, HHD, HHD);
    k_prep_w<<<(TBN * HHD + 255) / 256, 256, 0, stream>>>(Wc, wct, HHD, NCLS, TBN);

    dim3 gHid(HHD / TBN, (NNODES + TBM - 1) / TBM);   // (2, 391)
    dim3 gCls(1, (NNODES + TBM - 1) / TBM);           // (1, 391)
    int ga = (NNODES * NHEAD + 255) / 256;
    int gagg = NNODES / 8;            // 8 nodes/block (2 per wave)

    // layer 1
    k_mfma_gemm<float><<<gHid, 256, 0, stream>>>(x, w1t, nullptr, xh_h, nullptr,
                                                 NNODES, 128, HHD, HHD);
    k_alpha<<<ga, 256, 0, stream>>>(xh_h, a1s, a1d, as_, ad_);
    k_agg<<<gagg, 256, 0, stream>>>(xh_h, as_, ad_, row_ptr, esrc, b1, hbuf_h);

    // layer 2
    k_mfma_gemm<_Float16><<<gHid, 256, 0, stream>>>(hbuf_h, w2t, nullptr, xh_h, nullptr,
                                                    NNODES, HHD, HHD, HHD);
    k_alpha<<<ga, 256, 0, stream>>>(xh_h, a2s, a2d, as_, ad_);
    k_agg<<<gagg, 256, 0, stream>>>(xh_h, as_, ad_, row_ptr, esrc, b2, hbuf_h);

    // classifier
    k_mfma_gemm<_Float16><<<gCls, 256, 0, stream>>>(hbuf_h, wct, bc, nullptr, out,
                                                    NNODES, HHD, NCLS, NCLS);
}